// Round 1
// baseline (124.566 us; speedup 1.0000x reference)
//
#include <hip/hip_runtime.h>

#define NN 100000
#define NE 400000
#define S  32
#define B  4096
#define DF 128
#define DE 64
#define D  128
#define K1 192   // gemm1 LHS row: [e(64), fbar(128)]
#define K0 192   // gemm0 LHS row: [f(128), ebar(64)]
#define K2 256   // gemm2 LHS row: [h0(128), mh1(128)]

typedef __attribute__((ext_vector_type(8))) short bf16x8;
typedef __attribute__((ext_vector_type(4))) float f32x4;

__device__ __forceinline__ unsigned short f2bf(float x) {
  union { float f; unsigned int u; } v; v.f = x;
  unsigned int r = (v.u + 0x7FFFu + ((v.u >> 16) & 1u)) >> 16;
  return (unsigned short)r;
}

// ---------- A: fuse weights into bf16, transposed [n][k] ----------
// W0T[mp][n][k]: k<128 -> (prep_W @ Wn_self[mp,0])[k][n], k>=128 -> (edge_prep @ Wn_neigh[mp,0])[k-128][n]
// W1T[mp][n][k]: k<64  -> (edge_prep @ We_self[mp,0])[k][n], k>=64  -> (prep_W @ We_neigh[mp,0])[k-64][n]
// W2T[mp][n][k]: k<128 -> Wn_self[mp,1][k][n],               k>=128 -> Wn_neigh[mp,1][k-128][n]
__global__ void fuse_weights(const float* __restrict__ prep_W,
                             const float* __restrict__ edge_prep_W,
                             const float* __restrict__ Wn_self,
                             const float* __restrict__ Wn_neigh,
                             const float* __restrict__ We_self,
                             const float* __restrict__ We_neigh,
                             unsigned short* __restrict__ W0T,
                             unsigned short* __restrict__ W1T,
                             unsigned short* __restrict__ W2T) {
  int idx = blockIdx.x * 256 + threadIdx.x;
  const int NW01 = 2 * 128 * 192;
  if (idx < NW01) {
    int mp = idx / (128 * 192);
    int r  = idx % (128 * 192);
    int n = r / 192, k = r % 192;
    const float* wns = Wn_self  + (mp * 2 + 0) * 128 * 128;
    const float* wnn = Wn_neigh + (mp * 2 + 0) * 128 * 128;
    const float* wes = We_self  + (mp * 2 + 0) * 128 * 128;
    const float* wen = We_neigh + (mp * 2 + 0) * 128 * 128;
    const float* ep  = edge_prep_W + mp * 64 * 128;
    float a0 = 0.f, a1 = 0.f;
    if (k < 128) { for (int j = 0; j < 128; j++) a0 += prep_W[k * 128 + j] * wns[j * 128 + n]; }
    else         { int kk = k - 128; for (int j = 0; j < 128; j++) a0 += ep[kk * 128 + j] * wnn[j * 128 + n]; }
    if (k < 64)  { for (int j = 0; j < 128; j++) a1 += ep[k * 128 + j] * wes[j * 128 + n]; }
    else         { int kk = k - 64;  for (int j = 0; j < 128; j++) a1 += prep_W[kk * 128 + j] * wen[j * 128 + n]; }
    W0T[idx] = f2bf(a0);
    W1T[idx] = f2bf(a1);
  } else {
    int i2 = idx - NW01;
    if (i2 < 2 * 128 * 256) {
      int mp = i2 / (128 * 256);
      int r  = i2 % (128 * 256);
      int n = r / 256, k = r % 256;
      float v = (k < 128) ? Wn_self[((mp * 2 + 1) * 128 + k) * 128 + n]
                          : Wn_neigh[((mp * 2 + 1) * 128 + (k - 128)) * 128 + n];
      W2T[i2] = f2bf(v);
    }
  }
}

// ---------- B: build G0 = [feats[ids[b]](128), ebar(64)] f32 ----------
__global__ void gather0(const int* __restrict__ ids,
                        const float* __restrict__ feats,
                        const int* __restrict__ n2e0, const int* __restrict__ n2e1,
                        const float* __restrict__ ee0, const float* __restrict__ ee1,
                        float* __restrict__ G0) {
  int wg = blockIdx.x;       // 2 * 4096
  int mp = wg >> 12;
  int b  = wg & 4095;
  int t  = threadIdx.x;      // 64
  int id = ids[b];
  const int*   n2e = mp ? n2e1 : n2e0;
  const float* ee  = mp ? ee1 : ee0;
  float* g = G0 + ((size_t)(mp * B + b)) * K0;
  const float* f = feats + (size_t)id * DF;
  g[t]      = f[t];
  g[t + 64] = f[t + 64];
  const int* row = n2e + (size_t)id * S;
  float sacc = 0.f;
  for (int e = 0; e < S; e++) {
    int eid = row[e];
    sacc += ee[(size_t)eid * DE + t];
  }
  g[128 + t] = sacc * (1.f / 32.f);
}

// ---------- C: gathered GEMM1 (131072 x 192 @ 192 x 128) + relu + mean-pool(32) -> G2[:,128:256] ----------
#define C_KP  200   // Gt row pad (192+8)
#define C_WKP 104   // Wt half-K pad (96+8)
__global__ __launch_bounds__(256) void gemm1_pool(
    const int* __restrict__ ids,
    const int* __restrict__ n2e0, const int* __restrict__ n2e1,
    const int* __restrict__ adj0, const int* __restrict__ adj1,
    const float* __restrict__ ee0, const float* __restrict__ ee1,
    const float* __restrict__ feats,
    const unsigned short* __restrict__ W1T,
    float* __restrict__ G2) {
  __shared__ unsigned short Gt[64 * C_KP];
  __shared__ unsigned short Wt[128 * C_WKP];
  int wg   = blockIdx.x;     // 2 * 2048
  int mp   = wg >> 11;
  int tile = wg & 2047;
  const int*   n2e = mp ? n2e1 : n2e0;
  const int*   adj = mp ? adj1 : adj0;
  const float* ee  = mp ? ee1 : ee0;
  const unsigned short* Wsrc = W1T + (size_t)mp * 128 * K1;
  int t = threadIdx.x;

  // stage 64 gathered rows -> bf16 LDS: [e(64) | (fa+fb)/2 (128)]
  {
    int row = t >> 2, p = t & 3;
    int gr = tile * 64 + row;
    int seed = gr >> 5, s = gr & 31;
    int id  = ids[seed];
    int eid = n2e[(size_t)id * S + s];
    int na  = adj[(size_t)eid * 2 + 0];
    int nb  = adj[(size_t)eid * 2 + 1];
    unsigned short* grow = &Gt[row * C_KP];
    const float* ep = ee + (size_t)eid * DE + p * 16;
    for (int j = 0; j < 16; j += 4) {
      float4 v = *(const float4*)(ep + j);
      grow[p * 16 + j + 0] = f2bf(v.x);
      grow[p * 16 + j + 1] = f2bf(v.y);
      grow[p * 16 + j + 2] = f2bf(v.z);
      grow[p * 16 + j + 3] = f2bf(v.w);
    }
    const float* fa = feats + (size_t)na * DF + p * 32;
    const float* fb = feats + (size_t)nb * DF + p * 32;
    for (int j = 0; j < 32; j += 4) {
      float4 va = *(const float4*)(fa + j);
      float4 vb = *(const float4*)(fb + j);
      grow[64 + p * 32 + j + 0] = f2bf(0.5f * (va.x + vb.x));
      grow[64 + p * 32 + j + 1] = f2bf(0.5f * (va.y + vb.y));
      grow[64 + p * 32 + j + 2] = f2bf(0.5f * (va.z + vb.z));
      grow[64 + p * 32 + j + 3] = f2bf(0.5f * (va.w + vb.w));
    }
  }

  int wave = t >> 6, lane = t & 63;
  int wr = wave >> 1, wc = wave & 1;
  int l15 = lane & 15, l4 = lane >> 4;
  f32x4 acc[2][4] = {};

  for (int h = 0; h < 2; h++) {
    __syncthreads();  // h=0: no-op hazard-wise; h=1: protect Wt before overwrite
    for (int i = t * 8; i < 128 * 96; i += 2048) {
      int n = i / 96, kk = i % 96;
      *(uint4*)(&Wt[n * C_WKP + kk]) = *(const uint4*)(&Wsrc[n * K1 + h * 96 + kk]);
    }
    __syncthreads();  // Wt (and on h=0 also Gt) visible
    for (int ksl = 0; ksl < 3; ksl++) {
      int kgt = h * 96 + ksl * 32 + l4 * 8;
      int kwt = ksl * 32 + l4 * 8;
      bf16x8 af[2], bw[4];
      for (int mi = 0; mi < 2; mi++) {
        int r = wr * 32 + mi * 16 + l15;
        af[mi] = *(const bf16x8*)(&Gt[r * C_KP + kgt]);
      }
      for (int ni = 0; ni < 4; ni++) {
        int c = wc * 64 + ni * 16 + l15;
        bw[ni] = *(const bf16x8*)(&Wt[c * C_WKP + kwt]);
      }
      for (int mi = 0; mi < 2; mi++)
        for (int ni = 0; ni < 4; ni++)
          acc[mi][ni] = __builtin_amdgcn_mfma_f32_16x16x32_bf16(af[mi], bw[ni], acc[mi][ni], 0, 0, 0);
    }
  }

  // relu + mean over 32 rows (wave wr owns seed tile*2+wr entirely)
  int seed0 = tile * 2 + wr;
  float* g2 = G2 + ((size_t)(mp * B + seed0)) * K2 + 128;
  for (int ni = 0; ni < 4; ni++) {
    float ssum = 0.f;
    for (int mi = 0; mi < 2; mi++)
      for (int q = 0; q < 4; q++)
        ssum += fmaxf(acc[mi][ni][q], 0.f);
    ssum += __shfl_xor(ssum, 16);
    ssum += __shfl_xor(ssum, 32);
    if (l4 == 0) g2[wc * 64 + ni * 16 + l15] = ssum * (1.f / 32.f);
  }
}

// ---------- D/F: dense GEMM (4096 x K @ K x 128), relu, write out (+optional copy) ----------
template <int K>
__global__ __launch_bounds__(256) void gemm_dense(
    const float* __restrict__ G,             // [2][4096][K] f32
    const unsigned short* __restrict__ WT,   // [2][128][K] bf16
    float* __restrict__ outA,                // stride 256 rows (pre-offset for cols)
    float* __restrict__ outB) {              // optional, stride 256, or null
  const int KP  = K + 8;
  const int KH  = K / 2;
  const int KHP = KH + 8;
  __shared__ unsigned short Gt[32 * KP];
  __shared__ unsigned short Wt[128 * KHP];
  int wg   = blockIdx.x;       // 2 * 128
  int mp   = wg >> 7;
  int tile = wg & 127;
  const float* Gsrc = G + ((size_t)mp * B + tile * 32) * K;
  const unsigned short* Wsrc = WT + (size_t)mp * 128 * K;
  int t = threadIdx.x;

  for (int i = t * 4; i < 32 * K; i += 1024) {
    float4 v = *(const float4*)(Gsrc + i);
    int row = i / K, k = i % K;
    unsigned short* d = &Gt[row * KP + k];
    d[0] = f2bf(v.x); d[1] = f2bf(v.y); d[2] = f2bf(v.z); d[3] = f2bf(v.w);
  }

  int wave = t >> 6, lane = t & 63;
  int l15 = lane & 15, l4 = lane >> 4;
  f32x4 acc[2][2] = {};

  for (int h = 0; h < 2; h++) {
    __syncthreads();
    for (int i = t * 8; i < 128 * KH; i += 2048) {
      int n = i / KH, kk = i % KH;
      *(uint4*)(&Wt[n * KHP + kk]) = *(const uint4*)(&Wsrc[n * K + h * KH + kk]);
    }
    __syncthreads();
    for (int ksl = 0; ksl < KH / 32; ksl++) {
      int kgt = h * KH + ksl * 32 + l4 * 8;
      int kwt = ksl * 32 + l4 * 8;
      bf16x8 af[2], bw[2];
      for (int mi = 0; mi < 2; mi++)
        af[mi] = *(const bf16x8*)(&Gt[(mi * 16 + l15) * KP + kgt]);
      for (int ni = 0; ni < 2; ni++)
        bw[ni] = *(const bf16x8*)(&Wt[(wave * 32 + ni * 16 + l15) * KHP + kwt]);
      for (int mi = 0; mi < 2; mi++)
        for (int ni = 0; ni < 2; ni++)
          acc[mi][ni] = __builtin_amdgcn_mfma_f32_16x16x32_bf16(af[mi], bw[ni], acc[mi][ni], 0, 0, 0);
    }
  }

  for (int mi = 0; mi < 2; mi++)
    for (int ni = 0; ni < 2; ni++)
      for (int q = 0; q < 4; q++) {
        int row = mi * 16 + l4 * 4 + q;
        int col = wave * 32 + ni * 16 + l15;
        float v = fmaxf(acc[mi][ni][q], 0.f);
        size_t o = ((size_t)(mp * B) + tile * 32 + row) * 256 + col;
        outA[o] = v;
        if (outB) outB[o] = v;
      }
}

extern "C" void kernel_launch(void* const* d_in, const int* in_sizes, int n_in,
                              void* d_out, int out_size, void* d_ws, size_t ws_size,
                              hipStream_t stream) {
  (void)in_sizes; (void)n_in; (void)out_size; (void)ws_size;
  const int*   ids    = (const int*)d_in[0];
  const float* feats  = (const float*)d_in[1];
  const int*   n2e0   = (const int*)d_in[2];
  const int*   n2e1   = (const int*)d_in[3];
  const int*   adj0   = (const int*)d_in[4];
  const int*   adj1   = (const int*)d_in[5];
  const float* ee0    = (const float*)d_in[6];
  const float* ee1    = (const float*)d_in[7];
  const float* prep_W = (const float*)d_in[8];
  const float* eprep  = (const float*)d_in[9];
  const float* WnS    = (const float*)d_in[10];
  const float* WnN    = (const float*)d_in[11];
  const float* WeS    = (const float*)d_in[12];
  const float* WeN    = (const float*)d_in[13];
  float* out = (float*)d_out;

  char* ws = (char*)d_ws;
  unsigned short* W0T = (unsigned short*)(ws);                 // 2*128*192*2 = 98304 B
  unsigned short* W1T = (unsigned short*)(ws + 98304);         // 98304 B
  unsigned short* W2T = (unsigned short*)(ws + 196608);        // 2*128*256*2 = 131072 B
  float*          G0  = (float*)(ws + 327680);                 // 2*4096*192*4 = 6291456 B
  float*          G2  = (float*)(ws + 6619136);                // 2*4096*256*4 = 8388608 B

  hipLaunchKernelGGL(fuse_weights, dim3(448), dim3(256), 0, stream,
                     prep_W, eprep, WnS, WnN, WeS, WeN, W0T, W1T, W2T);
  hipLaunchKernelGGL(gather0, dim3(2 * B), dim3(64), 0, stream,
                     ids, feats, n2e0, n2e1, ee0, ee1, G0);
  hipLaunchKernelGGL(gemm1_pool, dim3(2 * 2048), dim3(256), 0, stream,
                     ids, n2e0, n2e1, adj0, adj1, ee0, ee1, feats, W1T, G2);
  hipLaunchKernelGGL((gemm_dense<192>), dim3(2 * 128), dim3(256), 0, stream,
                     G0, W0T, out, G2);
  hipLaunchKernelGGL((gemm_dense<256>), dim3(2 * 128), dim3(256), 0, stream,
                     G2, W2T, out + 128, (float*)nullptr);
}

// Round 2
// 112.679 us; speedup vs baseline: 1.1055x; 1.1055x over previous
//
#include <hip/hip_runtime.h>
#include <hip/hip_bf16.h>

#define NN 100000
#define NE 400000
#define S  32
#define B  4096
#define DF 128
#define DE 64
#define D  128
#define K1 192   // gemm1 LHS row: [e(64), fbar(128)]
#define K0 192   // gemm0 LHS row: [f(128), ebar(64)]
#define K2 256   // gemm2 LHS row: [h0(128), mh1(128)]

typedef __attribute__((ext_vector_type(8))) short bf16x8;
typedef __attribute__((ext_vector_type(4))) float f32x4;

__device__ __forceinline__ unsigned short f2bf(float x) {
  union { float f; unsigned int u; } v; v.f = x;
  unsigned int r = (v.u + 0x7FFFu + ((v.u >> 16) & 1u)) >> 16;
  return (unsigned short)r;
}

// packed f32x2 -> bf16x2 (compiler emits v_cvt_pk_bf16_f32)
__device__ __forceinline__ unsigned int pk2(float lo, float hi) {
  __hip_bfloat162 h = __float22bfloat162_rn(float2{lo, hi});
  union { __hip_bfloat162 h; unsigned int u; } c; c.h = h;
  return c.u;
}

// ---------- A: fuse weights into bf16 ----------
// W0T[mp][n][k]: k<128 -> (prep_W @ Wn_self[mp,0])[k][n], k>=128 -> (edge_prep @ Wn_neigh[mp,0])[k-128][n]
// W1F: fragment layout [mp][ksl(6)][l4(4)][col(128)][8] of
//      k<64 -> (edge_prep @ We_self[mp,0])[k][n], k>=64 -> (prep_W @ We_neigh[mp,0])[k-64][n]
// W2T[mp][n][k]: k<128 -> Wn_self[mp,1][k][n],    k>=128 -> Wn_neigh[mp,1][k-128][n]
__global__ void fuse_weights(const float* __restrict__ prep_W,
                             const float* __restrict__ edge_prep_W,
                             const float* __restrict__ Wn_self,
                             const float* __restrict__ Wn_neigh,
                             const float* __restrict__ We_self,
                             const float* __restrict__ We_neigh,
                             unsigned short* __restrict__ W0T,
                             unsigned short* __restrict__ W1F,
                             unsigned short* __restrict__ W2T) {
  int idx = blockIdx.x * 256 + threadIdx.x;
  const int NW01 = 2 * 128 * 192;
  if (idx < NW01) {
    int mp = idx / (128 * 192);
    int r  = idx % (128 * 192);
    int n = r / 192, k = r % 192;
    const float* wns = Wn_self  + (mp * 2 + 0) * 128 * 128;
    const float* wnn = Wn_neigh + (mp * 2 + 0) * 128 * 128;
    const float* wes = We_self  + (mp * 2 + 0) * 128 * 128;
    const float* wen = We_neigh + (mp * 2 + 0) * 128 * 128;
    const float* ep  = edge_prep_W + mp * 64 * 128;
    float a0 = 0.f, a1 = 0.f;
    if (k < 128) { for (int j = 0; j < 128; j++) a0 += prep_W[k * 128 + j] * wns[j * 128 + n]; }
    else         { int kk = k - 128; for (int j = 0; j < 128; j++) a0 += ep[kk * 128 + j] * wnn[j * 128 + n]; }
    if (k < 64)  { for (int j = 0; j < 128; j++) a1 += ep[k * 128 + j] * wes[j * 128 + n]; }
    else         { int kk = k - 64;  for (int j = 0; j < 128; j++) a1 += prep_W[kk * 128 + j] * wen[j * 128 + n]; }
    W0T[idx] = f2bf(a0);
    // fragment layout for W1
    int f  = k >> 5;
    int kk = k & 31;
    int l4 = kk >> 3, e = kk & 7;
    W1F[((((size_t)mp * 6 + f) * 4 + l4) * 128 + n) * 8 + e] = f2bf(a1);
  } else {
    int i2 = idx - NW01;
    if (i2 < 2 * 128 * 256) {
      int mp = i2 / (128 * 256);
      int r  = i2 % (128 * 256);
      int n = r / 256, k = r % 256;
      float v = (k < 128) ? Wn_self[((mp * 2 + 1) * 128 + k) * 128 + n]
                          : Wn_neigh[((mp * 2 + 1) * 128 + (k - 128)) * 128 + n];
      W2T[i2] = f2bf(v);
    }
  }
}

// ---------- B: build G0 = [feats[ids[b]](128), ebar(64)] f32 ----------
__global__ void gather0(const int* __restrict__ ids,
                        const float* __restrict__ feats,
                        const int* __restrict__ n2e0, const int* __restrict__ n2e1,
                        const float* __restrict__ ee0, const float* __restrict__ ee1,
                        float* __restrict__ G0) {
  int wg = blockIdx.x;       // 2 * 4096
  int mp = wg >> 12;
  int b  = wg & 4095;
  int t  = threadIdx.x;      // 64
  int id = ids[b];
  const int*   n2e = mp ? n2e1 : n2e0;
  const float* ee  = mp ? ee1 : ee0;
  float* g = G0 + ((size_t)(mp * B + b)) * K0;
  const float* f = feats + (size_t)id * DF;
  g[t]      = f[t];
  g[t + 64] = f[t + 64];
  const int* row = n2e + (size_t)id * S;
  float sacc = 0.f;
  for (int e = 0; e < S; e++) {
    int eid = row[e];
    sacc += ee[(size_t)eid * DE + t];
  }
  g[128 + t] = sacc * (1.f / 32.f);
}

// ---------- C: gathered GEMM1 (131072 x 192 @ 192 x 128) + relu + mean-pool(32) -> G2[:,128:256] ----------
#define C_KP  200   // Gt row pad (192+8 shorts)
__global__ __launch_bounds__(256, 6) void gemm1_pool(
    const int* __restrict__ ids,
    const int* __restrict__ n2e0, const int* __restrict__ n2e1,
    const int* __restrict__ adj0, const int* __restrict__ adj1,
    const float* __restrict__ ee0, const float* __restrict__ ee1,
    const float* __restrict__ feats,
    const unsigned short* __restrict__ W1F,
    float* __restrict__ G2) {
  __shared__ unsigned short Gt[64 * C_KP];   // 25.6 KB -> 6 blocks/CU
  int wg   = blockIdx.x;     // 2 * 2048
  int mp   = wg >> 11;
  int tile = wg & 2047;
  const int*   n2e = mp ? n2e1 : n2e0;
  const int*   adj = mp ? adj1 : adj0;
  const float* ee  = mp ? ee1 : ee0;
  const unsigned short* Wf = W1F + (size_t)mp * (6 * 4 * 128 * 8);
  int t = threadIdx.x;

  // stage 64 gathered rows -> bf16 LDS: [e(64) | (fa+fb)/2 (128)], packed writes
  {
    int row = t >> 2, p = t & 3;
    int gr = tile * 64 + row;
    int seed = gr >> 5, s = gr & 31;
    int id  = ids[seed];
    int eid = n2e[(size_t)id * S + s];
    int2 ab = *(const int2*)(adj + (size_t)eid * 2);
    unsigned short* grow = &Gt[row * C_KP];
    const float* ep = ee + (size_t)eid * DE + p * 16;
#pragma unroll
    for (int j = 0; j < 16; j += 4) {
      float4 v = *(const float4*)(ep + j);
      uint2 w;
      w.x = pk2(v.x, v.y);
      w.y = pk2(v.z, v.w);
      *(uint2*)(&grow[p * 16 + j]) = w;
    }
    const float* fa = feats + (size_t)ab.x * DF + p * 32;
    const float* fb = feats + (size_t)ab.y * DF + p * 32;
#pragma unroll
    for (int j = 0; j < 32; j += 4) {
      float4 va = *(const float4*)(fa + j);
      float4 vb = *(const float4*)(fb + j);
      uint2 w;
      w.x = pk2(0.5f * (va.x + vb.x), 0.5f * (va.y + vb.y));
      w.y = pk2(0.5f * (va.z + vb.z), 0.5f * (va.w + vb.w));
      *(uint2*)(&grow[64 + p * 32 + j]) = w;
    }
  }
  __syncthreads();

  int wave = t >> 6, lane = t & 63;
  int wr = wave >> 1, wc = wave & 1;
  int l15 = lane & 15, l4 = lane >> 4;
  f32x4 acc[2][4] = {};

#pragma unroll
  for (int ks = 0; ks < 6; ks++) {
    int kgt = ks * 32 + l4 * 8;
    bf16x8 af[2], bw[4];
#pragma unroll
    for (int mi = 0; mi < 2; mi++) {
      int r = wr * 32 + mi * 16 + l15;
      af[mi] = *(const bf16x8*)(&Gt[r * C_KP + kgt]);
    }
    const unsigned short* wb = Wf + (size_t)((ks * 4 + l4) * 128) * 8;
#pragma unroll
    for (int ni = 0; ni < 4; ni++) {
      int c = wc * 64 + ni * 16 + l15;
      bw[ni] = *(const bf16x8*)(wb + c * 8);
    }
#pragma unroll
    for (int mi = 0; mi < 2; mi++)
#pragma unroll
      for (int ni = 0; ni < 4; ni++)
        acc[mi][ni] = __builtin_amdgcn_mfma_f32_16x16x32_bf16(af[mi], bw[ni], acc[mi][ni], 0, 0, 0);
  }

  // relu + mean over 32 rows (wave wr owns seed tile*2+wr entirely)
  int seed0 = tile * 2 + wr;
  float* g2 = G2 + ((size_t)(mp * B + seed0)) * K2 + 128;
#pragma unroll
  for (int ni = 0; ni < 4; ni++) {
    float ssum = 0.f;
#pragma unroll
    for (int mi = 0; mi < 2; mi++)
#pragma unroll
      for (int q = 0; q < 4; q++)
        ssum += fmaxf(acc[mi][ni][q], 0.f);
    ssum += __shfl_xor(ssum, 16);
    ssum += __shfl_xor(ssum, 32);
    if (l4 == 0) g2[wc * 64 + ni * 16 + l15] = ssum * (1.f / 32.f);
  }
}

// ---------- D/F: dense GEMM (4096 x K @ K x 128), relu, write out (+optional copy) ----------
template <int K>
__global__ __launch_bounds__(256) void gemm_dense(
    const float* __restrict__ G,             // [2][4096][K] f32
    const unsigned short* __restrict__ WT,   // [2][128][K] bf16
    float* __restrict__ outA,                // stride 256 rows (pre-offset for cols)
    float* __restrict__ outB) {              // optional, stride 256, or null
  const int KP  = K + 8;
  const int KH  = K / 2;
  const int KHP = KH + 8;
  __shared__ unsigned short Gt[32 * KP];
  __shared__ unsigned short Wt[128 * KHP];
  int wg   = blockIdx.x;       // 2 * 128
  int mp   = wg >> 7;
  int tile = wg & 127;
  const float* Gsrc = G + ((size_t)mp * B + tile * 32) * K;
  const unsigned short* Wsrc = WT + (size_t)mp * 128 * K;
  int t = threadIdx.x;

  for (int i = t * 4; i < 32 * K; i += 1024) {
    float4 v = *(const float4*)(Gsrc + i);
    int row = i / K, k = i % K;
    uint2 w;
    w.x = pk2(v.x, v.y);
    w.y = pk2(v.z, v.w);
    *(uint2*)(&Gt[row * KP + k]) = w;
  }

  int wave = t >> 6, lane = t & 63;
  int l15 = lane & 15, l4 = lane >> 4;
  f32x4 acc[2][2] = {};

  for (int h = 0; h < 2; h++) {
    __syncthreads();
    for (int i = t * 8; i < 128 * KH; i += 2048) {
      int n = i / KH, kk = i % KH;
      *(uint4*)(&Wt[n * KHP + kk]) = *(const uint4*)(&Wsrc[n * K + h * KH + kk]);
    }
    __syncthreads();
    for (int ksl = 0; ksl < KH / 32; ksl++) {
      int kgt = h * KH + ksl * 32 + l4 * 8;
      int kwt = ksl * 32 + l4 * 8;
      bf16x8 af[2], bw[2];
      for (int mi = 0; mi < 2; mi++)
        af[mi] = *(const bf16x8*)(&Gt[(mi * 16 + l15) * KP + kgt]);
      for (int ni = 0; ni < 2; ni++)
        bw[ni] = *(const bf16x8*)(&Wt[(wave * 32 + ni * 16 + l15) * KHP + kwt]);
      for (int mi = 0; mi < 2; mi++)
        for (int ni = 0; ni < 2; ni++)
          acc[mi][ni] = __builtin_amdgcn_mfma_f32_16x16x32_bf16(af[mi], bw[ni], acc[mi][ni], 0, 0, 0);
    }
  }

  for (int mi = 0; mi < 2; mi++)
    for (int ni = 0; ni < 2; ni++)
      for (int q = 0; q < 4; q++) {
        int row = mi * 16 + l4 * 4 + q;
        int col = wave * 32 + ni * 16 + l15;
        float v = fmaxf(acc[mi][ni][q], 0.f);
        size_t o = ((size_t)(mp * B) + tile * 32 + row) * 256 + col;
        outA[o] = v;
        if (outB) outB[o] = v;
      }
}

extern "C" void kernel_launch(void* const* d_in, const int* in_sizes, int n_in,
                              void* d_out, int out_size, void* d_ws, size_t ws_size,
                              hipStream_t stream) {
  (void)in_sizes; (void)n_in; (void)out_size; (void)ws_size;
  const int*   ids    = (const int*)d_in[0];
  const float* feats  = (const float*)d_in[1];
  const int*   n2e0   = (const int*)d_in[2];
  const int*   n2e1   = (const int*)d_in[3];
  const int*   adj0   = (const int*)d_in[4];
  const int*   adj1   = (const int*)d_in[5];
  const float* ee0    = (const float*)d_in[6];
  const float* ee1    = (const float*)d_in[7];
  const float* prep_W = (const float*)d_in[8];
  const float* eprep  = (const float*)d_in[9];
  const float* WnS    = (const float*)d_in[10];
  const float* WnN    = (const float*)d_in[11];
  const float* WeS    = (const float*)d_in[12];
  const float* WeN    = (const float*)d_in[13];
  float* out = (float*)d_out;

  char* ws = (char*)d_ws;
  unsigned short* W0T = (unsigned short*)(ws);                 // 2*128*192*2 = 98304 B
  unsigned short* W1F = (unsigned short*)(ws + 98304);         // 2*6*4*128*8*2 = 98304 B
  unsigned short* W2T = (unsigned short*)(ws + 196608);        // 2*128*256*2 = 131072 B
  float*          G0  = (float*)(ws + 327680);                 // 2*4096*192*4 = 6291456 B
  float*          G2  = (float*)(ws + 6619136);                // 2*4096*256*4 = 8388608 B

  hipLaunchKernelGGL(fuse_weights, dim3(448), dim3(256), 0, stream,
                     prep_W, eprep, WnS, WnN, WeS, WeN, W0T, W1F, W2T);
  hipLaunchKernelGGL(gather0, dim3(2 * B), dim3(64), 0, stream,
                     ids, feats, n2e0, n2e1, ee0, ee1, G0);
  hipLaunchKernelGGL(gemm1_pool, dim3(2 * 2048), dim3(256), 0, stream,
                     ids, n2e0, n2e1, adj0, adj1, ee0, ee1, feats, W1F, G2);
  hipLaunchKernelGGL((gemm_dense<192>), dim3(2 * 128), dim3(256), 0, stream,
                     G0, W0T, out, G2);
  hipLaunchKernelGGL((gemm_dense<256>), dim3(2 * 128), dim3(256), 0, stream,
                     G2, W2T, out + 128, (float*)nullptr);
}

// Round 3
// 94.550 us; speedup vs baseline: 1.3175x; 1.1917x over previous
//
#include <hip/hip_runtime.h>
#include <hip/hip_bf16.h>

#define NN 100000
#define NE 400000
#define S  32
#define B  4096
#define DF 128
#define DE 64
#define D  128
#define K1 192   // gemm1 LHS row: [e(64), fbar(128)]
#define K0 192   // gemm0 LHS row: [f(128), ebar(64)]
#define K2 256   // gemm2 LHS row: [h0(128), mh1(128)]

typedef __attribute__((ext_vector_type(8))) short bf16x8;
typedef __attribute__((ext_vector_type(4))) float f32x4;

__device__ __forceinline__ unsigned short f2bf(float x) {
  union { float f; unsigned int u; } v; v.f = x;
  unsigned int r = (v.u + 0x7FFFu + ((v.u >> 16) & 1u)) >> 16;
  return (unsigned short)r;
}

// packed f32x2 -> bf16x2 (compiler emits v_cvt_pk_bf16_f32)
__device__ __forceinline__ unsigned int pk2(float lo, float hi) {
  __hip_bfloat162 h = __float22bfloat162_rn(float2{lo, hi});
  union { __hip_bfloat162 h; unsigned int u; } c; c.h = h;
  return c.u;
}

__device__ __forceinline__ bf16x8 pack8(float4 a, float4 b) {
  union { bf16x8 v; unsigned int u[4]; } c;
  c.u[0] = pk2(a.x, a.y); c.u[1] = pk2(a.z, a.w);
  c.u[2] = pk2(b.x, b.y); c.u[3] = pk2(b.z, b.w);
  return c.v;
}

// ---------- A: fuse weights into bf16 fragment layout ----------
// Fragment layout per matrix: [mp][ks(K/32)][l4(4)][col(128)][8 bf16]
// W0F (K=192): k<128 -> (prep_W @ Wn_self[mp,0])[k][n], k>=128 -> (edge_prep @ Wn_neigh[mp,0])[k-128][n]
// W1F (K=192): k<64  -> (edge_prep @ We_self[mp,0])[k][n], k>=64  -> (prep_W @ We_neigh[mp,0])[k-64][n]
// W2F (K=256): k<128 -> Wn_self[mp,1][k][n],               k>=128 -> Wn_neigh[mp,1][k-128][n]
__global__ __launch_bounds__(128) void fuse_weights(
    const float* __restrict__ prep_W, const float* __restrict__ edge_prep_W,
    const float* __restrict__ Wn_self, const float* __restrict__ Wn_neigh,
    const float* __restrict__ We_self, const float* __restrict__ We_neigh,
    unsigned short* __restrict__ W0F, unsigned short* __restrict__ W1F,
    unsigned short* __restrict__ W2F) {
  int wg = blockIdx.x;
  int n  = threadIdx.x;   // 128 = output col
  if (wg < 384) {
    int mp = wg / 192, k = wg % 192;
    const float* eprow = edge_prep_W + (size_t)mp * 64 * 128;
    const float* A0 = (k < 128) ? prep_W + (size_t)k * 128 : eprow + (size_t)(k - 128) * 128;
    const float* B0 = ((k < 128) ? Wn_self : Wn_neigh) + (size_t)(mp * 2) * 128 * 128;
    const float* A1 = (k < 64)  ? eprow + (size_t)k * 128 : prep_W + (size_t)(k - 64) * 128;
    const float* B1 = ((k < 64)  ? We_self : We_neigh) + (size_t)(mp * 2) * 128 * 128;
    __shared__ float sA0[128], sA1[128];
    sA0[n] = A0[n]; sA1[n] = A1[n];
    __syncthreads();
    float acc0 = 0.f, acc1 = 0.f;
#pragma unroll 8
    for (int j = 0; j < 128; j++) {
      acc0 += sA0[j] * B0[j * 128 + n];   // coalesced across threads
      acc1 += sA1[j] * B1[j * 128 + n];
    }
    int ks = k >> 5, l4 = (k >> 3) & 3, e = k & 7;
    W0F[(((size_t)(mp * 6 + ks) * 4 + l4) * 128 + n) * 8 + e] = f2bf(acc0);
    W1F[(((size_t)(mp * 6 + ks) * 4 + l4) * 128 + n) * 8 + e] = f2bf(acc1);
  } else {
    int w2 = wg - 384;            // 0..127
    int mp = w2 >> 6;
    int kb = (w2 & 63) * 4;
#pragma unroll
    for (int kk = 0; kk < 4; kk++) {
      int k = kb + kk;
      float v = (k < 128) ? Wn_self[(((size_t)(mp * 2) + 1) * 128 + k) * 128 + n]
                          : Wn_neigh[(((size_t)(mp * 2) + 1) * 128 + (k - 128)) * 128 + n];
      int ks = k >> 5, l4 = (k >> 3) & 3, e = k & 7;
      W2F[(((size_t)(mp * 8 + ks) * 4 + l4) * 128 + n) * 8 + e] = f2bf(v);
    }
  }
}

// ---------- C: gathered GEMM1 + relu + pool, fused ebar + feats copy ----------
// One seed per wave, 4 seeds per block. No LDS, no barriers.
// Writes: G2[mp*B+seed][128:256] (pooled relu), G0[mp*B+seed][0:192] ([feats, ebar]).
__global__ __launch_bounds__(256, 3) void gemm1_pool(
    const int* __restrict__ ids,
    const int* __restrict__ n2e0, const int* __restrict__ n2e1,
    const int* __restrict__ adj0, const int* __restrict__ adj1,
    const float* __restrict__ ee0, const float* __restrict__ ee1,
    const float* __restrict__ feats,
    const unsigned short* __restrict__ W1F,
    float* __restrict__ G0, float* __restrict__ G2) {
  int wg   = blockIdx.x;     // 2 * 1024
  int mp   = wg >> 10;
  int tile = wg & 1023;
  int wave = threadIdx.x >> 6, lane = threadIdx.x & 63;
  int l15 = lane & 15, l4 = lane >> 4;
  int seed = tile * 4 + wave;

  const int*   n2e = mp ? n2e1 : n2e0;
  const int*   adj = mp ? adj1 : adj0;
  const float* ee  = mp ? ee1 : ee0;

  int id = ids[seed];   // wave-uniform
  // lane handles edge rows s = l15 (mi=0) and 16+l15 (mi=1)
  int eidA = n2e[(size_t)id * S + l15];        // coalesced 128B over 16 lanes
  int eidB = n2e[(size_t)id * S + 16 + l15];
  int2 abA = *(const int2*)(adj + (size_t)eidA * 2);
  int2 abB = *(const int2*)(adj + (size_t)eidB * 2);
  int eids[2] = {eidA, eidB};
  int2 abx[2] = {abA, abB};

  bf16x8 a[2][6];          // A fragments: [mi][ks]
  float esum[2][8];        // f32 partial sums of raw ee (for ebar)
#pragma unroll
  for (int j = 0; j < 8; j++) { esum[0][j] = 0.f; esum[1][j] = 0.f; }

#pragma unroll
  for (int mi = 0; mi < 2; mi++) {
    const float* ep = ee + (size_t)eids[mi] * DE + l4 * 8;
#pragma unroll
    for (int ks = 0; ks < 2; ks++) {
      float4 v0 = *(const float4*)(ep + ks * 32);
      float4 v1 = *(const float4*)(ep + ks * 32 + 4);
      esum[ks][0] += v0.x; esum[ks][1] += v0.y; esum[ks][2] += v0.z; esum[ks][3] += v0.w;
      esum[ks][4] += v1.x; esum[ks][5] += v1.y; esum[ks][6] += v1.z; esum[ks][7] += v1.w;
      a[mi][ks] = pack8(v0, v1);
    }
    const float* fa = feats + (size_t)abx[mi].x * DF + l4 * 8;
    const float* fb = feats + (size_t)abx[mi].y * DF + l4 * 8;
#pragma unroll
    for (int ks = 2; ks < 6; ks++) {
      int off = (ks - 2) * 32;
      float4 a0 = *(const float4*)(fa + off);
      float4 a1 = *(const float4*)(fa + off + 4);
      float4 b0 = *(const float4*)(fb + off);
      float4 b1 = *(const float4*)(fb + off + 4);
      float4 m0, m1;
      m0.x = 0.5f * (a0.x + b0.x); m0.y = 0.5f * (a0.y + b0.y);
      m0.z = 0.5f * (a0.z + b0.z); m0.w = 0.5f * (a0.w + b0.w);
      m1.x = 0.5f * (a1.x + b1.x); m1.y = 0.5f * (a1.y + b1.y);
      m1.z = 0.5f * (a1.z + b1.z); m1.w = 0.5f * (a1.w + b1.w);
      a[mi][ks] = pack8(m0, m1);
    }
  }

  // MFMA: M=32 (2 mi), N=128 in two 64-col passes, K=192 (6 ks)
  const unsigned short* Wf = W1F + (size_t)mp * (6 * 4 * 128 * 8);
  float* G2row = G2 + ((size_t)(mp * B + seed)) * K2 + 128;
  for (int pass = 0; pass < 2; pass++) {
    f32x4 acc[2][4] = {};
#pragma unroll
    for (int ks = 0; ks < 6; ks++) {
      bf16x8 bw[4];
#pragma unroll
      for (int ni = 0; ni < 4; ni++) {
        int c = pass * 64 + ni * 16 + l15;
        bw[ni] = *(const bf16x8*)(Wf + ((size_t)((ks * 4 + l4) * 128 + c)) * 8);
      }
#pragma unroll
      for (int mi = 0; mi < 2; mi++)
#pragma unroll
        for (int ni = 0; ni < 4; ni++)
          acc[mi][ni] = __builtin_amdgcn_mfma_f32_16x16x32_bf16(a[mi][ks], bw[ni], acc[mi][ni], 0, 0, 0);
    }
    // relu + mean over 32 edge rows: rows = l4*4+q (+16mi), cross-lane over l4
#pragma unroll
    for (int ni = 0; ni < 4; ni++) {
      float ssum = 0.f;
#pragma unroll
      for (int mi = 0; mi < 2; mi++)
#pragma unroll
        for (int q = 0; q < 4; q++)
          ssum += fmaxf(acc[mi][ni][q], 0.f);
      ssum += __shfl_xor(ssum, 16);
      ssum += __shfl_xor(ssum, 32);
      if (l4 == 0) G2row[pass * 64 + ni * 16 + l15] = ssum * (1.f / 32.f);
    }
  }

  // ebar: reduce esum over the 16 l15 lanes (32 edges incl. both mi)
#pragma unroll
  for (int ks = 0; ks < 2; ks++)
#pragma unroll
    for (int j = 0; j < 8; j++) {
      float v = esum[ks][j];
      v += __shfl_xor(v, 1); v += __shfl_xor(v, 2);
      v += __shfl_xor(v, 4); v += __shfl_xor(v, 8);
      esum[ks][j] = v;
    }
  float* G0row = G0 + ((size_t)(mp * B + seed)) * K0;
  if (l15 == 0) {
#pragma unroll
    for (int ks = 0; ks < 2; ks++)
#pragma unroll
      for (int j = 0; j < 8; j++)
        G0row[128 + ks * 32 + l4 * 8 + j] = esum[ks][j] * (1.f / 32.f);
  }
  // feats copy: G0[seed][0:128] = feats[id]
  float2 fv = *((const float2*)(feats + (size_t)id * DF) + lane);
  *((float2*)G0row + lane) = fv;
}

// ---------- D/F: dense GEMM (4096 x K @ K x 128), relu, write out ----------
template <int K>
__global__ __launch_bounds__(256) void gemm_dense(
    const float* __restrict__ G,             // [2][4096][K] f32
    const unsigned short* __restrict__ WF,   // fragment layout [mp][K/32][4][128][8]
    float* __restrict__ outA,                // stride 256 rows (pre-offset for cols)
    float* __restrict__ outB) {              // optional copy, or null
  const int KP = K + 8;
  const int KS = K / 32;
  __shared__ unsigned short Gt[32 * KP];
  int wg   = blockIdx.x;       // 2 * 128
  int mp   = wg >> 7;
  int tile = wg & 127;
  const float* Gsrc = G + ((size_t)mp * B + tile * 32) * K;
  const unsigned short* Wf = WF + (size_t)mp * KS * 4 * 128 * 8;
  int t = threadIdx.x;

  for (int i = t * 4; i < 32 * K; i += 1024) {
    float4 v = *(const float4*)(Gsrc + i);
    int row = i / K, k = i % K;
    uint2 w; w.x = pk2(v.x, v.y); w.y = pk2(v.z, v.w);
    *(uint2*)(&Gt[row * KP + k]) = w;
  }
  __syncthreads();

  int wave = t >> 6, lane = t & 63;
  int l15 = lane & 15, l4 = lane >> 4;
  f32x4 acc[2][2] = {};
#pragma unroll
  for (int ks = 0; ks < KS; ks++) {
    bf16x8 af[2], bw[2];
#pragma unroll
    for (int mi = 0; mi < 2; mi++)
      af[mi] = *(const bf16x8*)(&Gt[(mi * 16 + l15) * KP + ks * 32 + l4 * 8]);
#pragma unroll
    for (int ni = 0; ni < 2; ni++) {
      int c = wave * 32 + ni * 16 + l15;
      bw[ni] = *(const bf16x8*)(Wf + ((size_t)((ks * 4 + l4) * 128 + c)) * 8);
    }
#pragma unroll
    for (int mi = 0; mi < 2; mi++)
#pragma unroll
      for (int ni = 0; ni < 2; ni++)
        acc[mi][ni] = __builtin_amdgcn_mfma_f32_16x16x32_bf16(af[mi], bw[ni], acc[mi][ni], 0, 0, 0);
  }

#pragma unroll
  for (int mi = 0; mi < 2; mi++)
#pragma unroll
    for (int ni = 0; ni < 2; ni++)
#pragma unroll
      for (int q = 0; q < 4; q++) {
        int row = mi * 16 + l4 * 4 + q;
        int col = wave * 32 + ni * 16 + l15;
        float v = fmaxf(acc[mi][ni][q], 0.f);
        size_t o = ((size_t)(mp * B) + tile * 32 + row) * 256 + col;
        outA[o] = v;
        if (outB) outB[o] = v;
      }
}

extern "C" void kernel_launch(void* const* d_in, const int* in_sizes, int n_in,
                              void* d_out, int out_size, void* d_ws, size_t ws_size,
                              hipStream_t stream) {
  (void)in_sizes; (void)n_in; (void)out_size; (void)ws_size;
  const int*   ids    = (const int*)d_in[0];
  const float* feats  = (const float*)d_in[1];
  const int*   n2e0   = (const int*)d_in[2];
  const int*   n2e1   = (const int*)d_in[3];
  const int*   adj0   = (const int*)d_in[4];
  const int*   adj1   = (const int*)d_in[5];
  const float* ee0    = (const float*)d_in[6];
  const float* ee1    = (const float*)d_in[7];
  const float* prep_W = (const float*)d_in[8];
  const float* eprep  = (const float*)d_in[9];
  const float* WnS    = (const float*)d_in[10];
  const float* WnN    = (const float*)d_in[11];
  const float* WeS    = (const float*)d_in[12];
  const float* WeN    = (const float*)d_in[13];
  float* out = (float*)d_out;

  char* ws = (char*)d_ws;
  unsigned short* W0F = (unsigned short*)(ws);                 // 2*6*4*128*8*2 = 98304 B
  unsigned short* W1F = (unsigned short*)(ws + 98304);         // 98304 B
  unsigned short* W2F = (unsigned short*)(ws + 196608);        // 2*8*4*128*8*2 = 131072 B
  float*          G0  = (float*)(ws + 327680);                 // 2*4096*192*4 = 6291456 B
  float*          G2  = (float*)(ws + 6619136);                // 2*4096*256*4 = 8388608 B

  hipLaunchKernelGGL(fuse_weights, dim3(512), dim3(128), 0, stream,
                     prep_W, eprep, WnS, WnN, WeS, WeN, W0F, W1F, W2F);
  hipLaunchKernelGGL(gemm1_pool, dim3(2 * 1024), dim3(256), 0, stream,
                     ids, n2e0, n2e1, adj0, adj1, ee0, ee1, feats, W1F, G0, G2);
  hipLaunchKernelGGL((gemm_dense<192>), dim3(2 * 128), dim3(256), 0, stream,
                     G0, W0F, out, G2);
  hipLaunchKernelGGL((gemm_dense<256>), dim3(2 * 128), dim3(256), 0, stream,
                     G2, W2F, out + 128, (float*)nullptr);
}

// Round 4
// 82.039 us; speedup vs baseline: 1.5184x; 1.1525x over previous
//
#include <hip/hip_runtime.h>
#include <hip/hip_bf16.h>

#define NN 100000
#define NE 400000
#define S  32
#define B  4096
#define DF 128
#define DE 64
#define D  128
#define K1 192   // gemm1 LHS row: [e(64), fbar(128)]
#define K0 192   // gemm0 LHS row: [f(128), ebar(64)]
#define K2 256   // gemm2 LHS row: [h0(128), mh1(128)]

typedef __attribute__((ext_vector_type(8))) short bf16x8;
typedef __attribute__((ext_vector_type(4))) float f32x4;

__device__ __forceinline__ unsigned short f2bf(float x) {
  union { float f; unsigned int u; } v; v.f = x;
  unsigned int r = (v.u + 0x7FFFu + ((v.u >> 16) & 1u)) >> 16;
  return (unsigned short)r;
}

__device__ __forceinline__ float bf2f(unsigned short s) {
  union { float f; unsigned int u; } v; v.u = ((unsigned int)s) << 16;
  return v.f;
}

// packed f32x2 -> bf16x2 (compiler emits v_cvt_pk_bf16_f32)
__device__ __forceinline__ unsigned int pk2(float lo, float hi) {
  __hip_bfloat162 h = __float22bfloat162_rn(float2{lo, hi});
  union { __hip_bfloat162 h; unsigned int u; } c; c.h = h;
  return c.u;
}

__device__ __forceinline__ bf16x8 pack8(float4 a, float4 b) {
  union { bf16x8 v; unsigned int u[4]; } c;
  c.u[0] = pk2(a.x, a.y); c.u[1] = pk2(a.z, a.w);
  c.u[2] = pk2(b.x, b.y); c.u[3] = pk2(b.z, b.w);
  return c.v;
}

// average two bf16x8 vectors (f32 math, repack)
__device__ __forceinline__ bf16x8 avg8(bf16x8 A, bf16x8 Bv) {
  union { bf16x8 v; unsigned short s[8]; } ua, ub;
  union { bf16x8 v; unsigned int u[4]; } uo;
  ua.v = A; ub.v = Bv;
#pragma unroll
  for (int p = 0; p < 4; p++) {
    float x0 = 0.5f * (bf2f(ua.s[2 * p]) + bf2f(ub.s[2 * p]));
    float x1 = 0.5f * (bf2f(ua.s[2 * p + 1]) + bf2f(ub.s[2 * p + 1]));
    uo.u[p] = pk2(x0, x1);
  }
  return uo.v;
}

// ---------- feats f32 -> bf16 (streaming) ----------
__global__ __launch_bounds__(256) void cvt_feats(const float* __restrict__ feats,
                                                 unsigned short* __restrict__ fb) {
  const int n = NN * DF / 8;
  for (int i = blockIdx.x * 256 + threadIdx.x; i < n; i += gridDim.x * 256) {
    const float4* s = (const float4*)(feats + (size_t)i * 8);
    float4 v0 = s[0], v1 = s[1];
    *(bf16x8*)(fb + (size_t)i * 8) = pack8(v0, v1);
  }
}

// ---------- A: fuse weights into bf16 fragment layout ----------
// Fragment layout per matrix: [mp][ks(K/32)][l4(4)][col(128)][8 bf16]
__global__ __launch_bounds__(128) void fuse_weights(
    const float* __restrict__ prep_W, const float* __restrict__ edge_prep_W,
    const float* __restrict__ Wn_self, const float* __restrict__ Wn_neigh,
    const float* __restrict__ We_self, const float* __restrict__ We_neigh,
    unsigned short* __restrict__ W0F, unsigned short* __restrict__ W1F,
    unsigned short* __restrict__ W2F) {
  int wg = blockIdx.x;
  int n  = threadIdx.x;   // 128 = output col
  if (wg < 384) {
    int mp = wg / 192, k = wg % 192;
    const float* eprow = edge_prep_W + (size_t)mp * 64 * 128;
    const float* A0 = (k < 128) ? prep_W + (size_t)k * 128 : eprow + (size_t)(k - 128) * 128;
    const float* B0 = ((k < 128) ? Wn_self : Wn_neigh) + (size_t)(mp * 2) * 128 * 128;
    const float* A1 = (k < 64)  ? eprow + (size_t)k * 128 : prep_W + (size_t)(k - 64) * 128;
    const float* B1 = ((k < 64)  ? We_self : We_neigh) + (size_t)(mp * 2) * 128 * 128;
    __shared__ float sA0[128], sA1[128];
    sA0[n] = A0[n]; sA1[n] = A1[n];
    __syncthreads();
    float acc0 = 0.f, acc1 = 0.f;
#pragma unroll 8
    for (int j = 0; j < 128; j++) {
      acc0 += sA0[j] * B0[j * 128 + n];
      acc1 += sA1[j] * B1[j * 128 + n];
    }
    int ks = k >> 5, l4 = (k >> 3) & 3, e = k & 7;
    W0F[(((size_t)(mp * 6 + ks) * 4 + l4) * 128 + n) * 8 + e] = f2bf(acc0);
    W1F[(((size_t)(mp * 6 + ks) * 4 + l4) * 128 + n) * 8 + e] = f2bf(acc1);
  } else {
    int w2 = wg - 384;            // 0..127
    int mp = w2 >> 6;
    int kb = (w2 & 63) * 4;
#pragma unroll
    for (int kk = 0; kk < 4; kk++) {
      int k = kb + kk;
      float v = (k < 128) ? Wn_self[(((size_t)(mp * 2) + 1) * 128 + k) * 128 + n]
                          : Wn_neigh[(((size_t)(mp * 2) + 1) * 128 + (k - 128)) * 128 + n];
      int ks = k >> 5, l4 = (k >> 3) & 3, e = k & 7;
      W2F[(((size_t)(mp * 8 + ks) * 4 + l4) * 128 + n) * 8 + e] = f2bf(v);
    }
  }
}

// ---------- C: gathered GEMM1 + relu + pool, fused ebar + feats copy ----------
// One seed per wave, 4 seeds/block. W in LDS (staged once). bf16 outputs.
__global__ __launch_bounds__(256, 3) void gemm1_pool(
    const int* __restrict__ ids,
    const int* __restrict__ n2e0, const int* __restrict__ n2e1,
    const int* __restrict__ adj0, const int* __restrict__ adj1,
    const float* __restrict__ ee0, const float* __restrict__ ee1,
    const unsigned short* __restrict__ featsbf,
    const unsigned short* __restrict__ W1F,
    unsigned short* __restrict__ G0, unsigned short* __restrict__ G2) {
  __shared__ unsigned short sW[6 * 4 * 128 * 8];   // 49152 B -> 3 blocks/CU
  int wg   = blockIdx.x;     // 2 * 1024
  int mp   = wg >> 10;
  int tile = wg & 1023;
  int wave = threadIdx.x >> 6, lane = threadIdx.x & 63;
  int l15 = lane & 15, l4 = lane >> 4;
  int seed = tile * 4 + wave;

  const int*   n2e = mp ? n2e1 : n2e0;
  const int*   adj = mp ? adj1 : adj0;
  const float* ee  = mp ? ee1 : ee0;

  // stage W fragments (L2-resident) -> LDS, coalesced
  {
    const uint4* src = (const uint4*)(W1F + (size_t)mp * 24576);
    uint4* dst = (uint4*)sW;
    for (int u = threadIdx.x; u < 3072; u += 256) dst[u] = src[u];
  }

  int id = ids[seed];   // wave-uniform
  int eidA = n2e[(size_t)id * S + l15];
  int eidB = n2e[(size_t)id * S + 16 + l15];
  int2 abA = *(const int2*)(adj + (size_t)eidA * 2);
  int2 abB = *(const int2*)(adj + (size_t)eidB * 2);
  int eids[2] = {eidA, eidB};
  int2 abx[2] = {abA, abB};

  bf16x8 a[2][6];          // A fragments: [mi][ks]
  float esum[2][8];        // f32 partial sums of raw ee (for ebar)
#pragma unroll
  for (int j = 0; j < 8; j++) { esum[0][j] = 0.f; esum[1][j] = 0.f; }

#pragma unroll
  for (int mi = 0; mi < 2; mi++) {
    const float* ep = ee + (size_t)eids[mi] * DE + l4 * 8;
#pragma unroll
    for (int ks = 0; ks < 2; ks++) {
      float4 v0 = *(const float4*)(ep + ks * 32);
      float4 v1 = *(const float4*)(ep + ks * 32 + 4);
      esum[ks][0] += v0.x; esum[ks][1] += v0.y; esum[ks][2] += v0.z; esum[ks][3] += v0.w;
      esum[ks][4] += v1.x; esum[ks][5] += v1.y; esum[ks][6] += v1.z; esum[ks][7] += v1.w;
      a[mi][ks] = pack8(v0, v1);
    }
    const unsigned short* fa = featsbf + (size_t)abx[mi].x * DF + l4 * 8;
    const unsigned short* fb = featsbf + (size_t)abx[mi].y * DF + l4 * 8;
#pragma unroll
    for (int ks = 2; ks < 6; ks++) {
      int off = (ks - 2) * 32;
      bf16x8 va = *(const bf16x8*)(fa + off);
      bf16x8 vb = *(const bf16x8*)(fb + off);
      a[mi][ks] = avg8(va, vb);
    }
  }

  __syncthreads();   // sW visible

  // MFMA: M=32 (2 mi), N=128 in two 64-col passes, K=192 (6 ks)
  unsigned short* G2row = G2 + ((size_t)(mp * B + seed)) * K2 + 128;
  for (int pass = 0; pass < 2; pass++) {
    f32x4 acc[2][4] = {};
#pragma unroll
    for (int ks = 0; ks < 6; ks++) {
      bf16x8 bw[4];
#pragma unroll
      for (int ni = 0; ni < 4; ni++) {
        int c = pass * 64 + ni * 16 + l15;
        bw[ni] = *(const bf16x8*)(sW + ((size_t)((ks * 4 + l4) * 128 + c)) * 8);
      }
#pragma unroll
      for (int mi = 0; mi < 2; mi++)
#pragma unroll
        for (int ni = 0; ni < 4; ni++)
          acc[mi][ni] = __builtin_amdgcn_mfma_f32_16x16x32_bf16(a[mi][ks], bw[ni], acc[mi][ni], 0, 0, 0);
    }
    // relu + mean over 32 edge rows
#pragma unroll
    for (int ni = 0; ni < 4; ni++) {
      float ssum = 0.f;
#pragma unroll
      for (int mi = 0; mi < 2; mi++)
#pragma unroll
        for (int q = 0; q < 4; q++)
          ssum += fmaxf(acc[mi][ni][q], 0.f);
      ssum += __shfl_xor(ssum, 16);
      ssum += __shfl_xor(ssum, 32);
      if (l4 == 0) G2row[pass * 64 + ni * 16 + l15] = f2bf(ssum * (1.f / 32.f));
    }
  }

  // ebar: butterfly over the 16 l15 lanes (all lanes get their l4-group sum)
#pragma unroll
  for (int ks = 0; ks < 2; ks++)
#pragma unroll
    for (int j = 0; j < 8; j++) {
      float v = esum[ks][j];
      v += __shfl_xor(v, 1); v += __shfl_xor(v, 2);
      v += __shfl_xor(v, 4); v += __shfl_xor(v, 8);
      esum[ks][j] = v;
    }
  unsigned short* G0row = G0 + ((size_t)(mp * B + seed)) * K0;
  if (l15 == 0) {
#pragma unroll
    for (int ks = 0; ks < 2; ks++) {
      float4 lo, hi;
      lo.x = esum[ks][0] * (1.f / 32.f); lo.y = esum[ks][1] * (1.f / 32.f);
      lo.z = esum[ks][2] * (1.f / 32.f); lo.w = esum[ks][3] * (1.f / 32.f);
      hi.x = esum[ks][4] * (1.f / 32.f); hi.y = esum[ks][5] * (1.f / 32.f);
      hi.z = esum[ks][6] * (1.f / 32.f); hi.w = esum[ks][7] * (1.f / 32.f);
      *(bf16x8*)(G0row + 128 + ks * 32 + l4 * 8) = pack8(lo, hi);
    }
  }
  // feats copy: G0[seed][0:128] = featsbf[id] (one coalesced 256B store/wave)
  ((unsigned int*)G0row)[lane] = ((const unsigned int*)(featsbf + (size_t)id * DF))[lane];
}

// ---------- D/F: dense GEMM (4096 x K @ K x 128), relu, write out ----------
template <int K>
__global__ __launch_bounds__(256) void gemm_dense(
    const unsigned short* __restrict__ G,    // [2][4096][K] bf16
    const unsigned short* __restrict__ WF,   // fragment layout [mp][K/32][4][128][8]
    float* __restrict__ outA,                // stride 256 rows (pre-offset for cols)
    unsigned short* __restrict__ outB16) {   // optional bf16 copy (G2 cols 0:128), or null
  const int KP = K + 8;
  const int KS = K / 32;
  __shared__ unsigned short Gt[32 * KP];
  int wg   = blockIdx.x;       // 2 * 128
  int mp   = wg >> 7;
  int tile = wg & 127;
  const unsigned short* Gsrc = G + ((size_t)mp * B + tile * 32) * K;
  const unsigned short* Wf = WF + (size_t)mp * KS * 4 * 128 * 8;
  int t = threadIdx.x;

  const int NU = 32 * K / 8;   // uint4 chunks
  for (int u = t; u < NU; u += 256) {
    int row = u / (K / 8), col = u % (K / 8);
    *(uint4*)(&Gt[row * KP + col * 8]) = *(const uint4*)(Gsrc + (size_t)row * K + col * 8);
  }
  __syncthreads();

  int wave = t >> 6, lane = t & 63;
  int l15 = lane & 15, l4 = lane >> 4;
  f32x4 acc[2][2] = {};
#pragma unroll
  for (int ks = 0; ks < KS; ks++) {
    bf16x8 af[2], bw[2];
#pragma unroll
    for (int mi = 0; mi < 2; mi++)
      af[mi] = *(const bf16x8*)(&Gt[(mi * 16 + l15) * KP + ks * 32 + l4 * 8]);
#pragma unroll
    for (int ni = 0; ni < 2; ni++) {
      int c = wave * 32 + ni * 16 + l15;
      bw[ni] = *(const bf16x8*)(Wf + ((size_t)((ks * 4 + l4) * 128 + c)) * 8);
    }
#pragma unroll
    for (int mi = 0; mi < 2; mi++)
#pragma unroll
      for (int ni = 0; ni < 2; ni++)
        acc[mi][ni] = __builtin_amdgcn_mfma_f32_16x16x32_bf16(af[mi], bw[ni], acc[mi][ni], 0, 0, 0);
  }

#pragma unroll
  for (int mi = 0; mi < 2; mi++)
#pragma unroll
    for (int ni = 0; ni < 2; ni++)
#pragma unroll
      for (int q = 0; q < 4; q++) {
        int row = mi * 16 + l4 * 4 + q;
        int col = wave * 32 + ni * 16 + l15;
        float v = fmaxf(acc[mi][ni][q], 0.f);
        size_t r = (size_t)(mp * B) + tile * 32 + row;
        outA[r * 256 + col] = v;
        if (outB16) outB16[r * 256 + col] = f2bf(v);
      }
}

extern "C" void kernel_launch(void* const* d_in, const int* in_sizes, int n_in,
                              void* d_out, int out_size, void* d_ws, size_t ws_size,
                              hipStream_t stream) {
  (void)in_sizes; (void)n_in; (void)out_size; (void)ws_size;
  const int*   ids    = (const int*)d_in[0];
  const float* feats  = (const float*)d_in[1];
  const int*   n2e0   = (const int*)d_in[2];
  const int*   n2e1   = (const int*)d_in[3];
  const int*   adj0   = (const int*)d_in[4];
  const int*   adj1   = (const int*)d_in[5];
  const float* ee0    = (const float*)d_in[6];
  const float* ee1    = (const float*)d_in[7];
  const float* prep_W = (const float*)d_in[8];
  const float* eprep  = (const float*)d_in[9];
  const float* WnS    = (const float*)d_in[10];
  const float* WnN    = (const float*)d_in[11];
  const float* WeS    = (const float*)d_in[12];
  const float* WeN    = (const float*)d_in[13];
  float* out = (float*)d_out;

  char* ws = (char*)d_ws;
  unsigned short* featsbf = (unsigned short*)(ws);                  // 100000*128*2 = 25,600,000 B
  unsigned short* W0F = (unsigned short*)(ws + 25600000);           // 98304 B
  unsigned short* W1F = (unsigned short*)(ws + 25698304);           // 98304 B
  unsigned short* W2F = (unsigned short*)(ws + 25796608);           // 131072 B
  unsigned short* G0  = (unsigned short*)(ws + 25927680);           // 2*4096*192*2 = 3,145,728 B
  unsigned short* G2  = (unsigned short*)(ws + 29073408);           // 2*4096*256*2 = 4,194,304 B

  hipLaunchKernelGGL(fuse_weights, dim3(512), dim3(128), 0, stream,
                     prep_W, eprep, WnS, WnN, WeS, WeN, W0F, W1F, W2F);
  hipLaunchKernelGGL(cvt_feats, dim3(2048), dim3(256), 0, stream, feats, featsbf);
  hipLaunchKernelGGL(gemm1_pool, dim3(2 * 1024), dim3(256), 0, stream,
                     ids, n2e0, n2e1, adj0, adj1, ee0, ee1, featsbf, W1F, G0, G2);
  hipLaunchKernelGGL((gemm_dense<192>), dim3(2 * 128), dim3(256), 0, stream,
                     G0, W0F, out, G2);
  hipLaunchKernelGGL((gemm_dense<256>), dim3(2 * 128), dim3(256), 0, stream,
                     G2, W2F, out + 128, (unsigned short*)nullptr);
}